// Round 10
// baseline (198.606 us; speedup 1.0000x reference)
//
#include <hip/hip_runtime.h>
#include <hip/hip_bf16.h>

// DTWLoss: out[b] = softDTW(sqdist(x,y)) - 0.5*(softDTW(sqdist(x,x)) + softDTW(sqdist(y,y)))
// B=64, N=M=512, F=256, gamma=0.1, BIG=1e8. Output: 64 fp32.
//
// Phase 1: convert x,y to bf16 + fp32 row norms.
// Phase 2: 192 batched MFMA GEMMs, 128x128 tile, LDS dbuf, staircase-layout
//          D (chunk (s,t): s=j+(i>>3), t=i>>3 at elems (s*64+t)*8+(i&7)),
//          full-128B-line stores, XCD-contiguous work remap (gemm <54us).
// Phase 3: wavefront DTW (hardmin; |softmin-min|<=gamma*ln3/cell, total <=112
//          vs 5242.88 threshold). R9 landed 54us (225cy/step) via issue-cut;
//          accounting: ~108cy issue + ~70cy chain + ~25cy EXPOSED lgkm (the
//          group drained lgkmcnt(0) right after issuing 8 ds_reads) + misc.
//          R10: (a) register double-buffer the slot reads -- read group g+1
//          into nxt regs BEFORE computing group g; lgkm drain (only needed to
//          free the slot for DMA reissue) lands after ~180cy of compute ->
//          latency hidden; DMA reissue moves after the drain (still 6-group
//          cover). (b) widen FAST to groups 8..63 (j==0 only in s<=63;
//          j>511 only in s>=512).

#define SDTW_BIG   1e8f
#define LDA 40        // LDS row stride in shorts (32 + 8 pad)
#define DROWS 576     // staircase rows allocated per matrix (575 used + pad)
#define DMAT_ELEMS (DROWS * 512)   // 294912 elems = 589824 B per matrix

typedef __attribute__((ext_vector_type(8))) short short8;   // 8 bf16
typedef __attribute__((ext_vector_type(4))) float floatx4;  // mfma acc

__device__ __forceinline__ unsigned short f2bf(float f) {
    __hip_bfloat16 h = __float2bfloat16(f);
    return *reinterpret_cast<unsigned short*>(&h);
}
__device__ __forceinline__ float bf2f_lo(unsigned int u) {
    return __uint_as_float(u << 16);
}
__device__ __forceinline__ float bf2f_hi(unsigned int u) {
    return __uint_as_float(u & 0xFFFF0000u);
}

// shfl_up(x,1) as DPP wave_shr:1 (0x138): lane i <- lane i-1, pure VALU.
// Lane 0 keeps old (=x); caller overrides t==0.
__device__ __forceinline__ float dpp_shr1(float x) {
    const int xi = __float_as_int(x);
    const int r = __builtin_amdgcn_update_dpp(xi, xi, 0x138, 0xf, 0xf, false);
    return __int_as_float(r);
}

// async global->LDS DMA, 16B per lane. LDS dest is wave-uniform base; HW adds
// lane*16. Global src is PER-LANE (each lane's own VGPR address).
__device__ __forceinline__ void gload16(const unsigned short* g, void* l) {
    __builtin_amdgcn_global_load_lds(
        (const __attribute__((address_space(1))) void*)g,
        (__attribute__((address_space(3))) void*)l, 16, 0, 0);
}

// ---- Phase 1: fp32 -> bf16 + row sum-of-squares (fp32) --------------------
__global__ __launch_bounds__(256) void convert_norm_kernel(
    const float* __restrict__ x, const float* __restrict__ y,
    unsigned short* __restrict__ xb, unsigned short* __restrict__ yb,
    float* __restrict__ nx, float* __restrict__ ny) {
    const float* src = blockIdx.y ? y : x;
    unsigned short* dst = blockIdx.y ? yb : xb;
    float* nrm = blockIdx.y ? ny : nx;
    const int wave = threadIdx.x >> 6;
    const int lane = threadIdx.x & 63;
    const int row  = blockIdx.x * 4 + wave;          // 0..32767
    const float4 v = reinterpret_cast<const float4*>(src + (size_t)row * 256)[lane];
    float ss = v.x * v.x + v.y * v.y + v.z * v.z + v.w * v.w;
    ushort4 u;
    u.x = f2bf(v.x); u.y = f2bf(v.y); u.z = f2bf(v.z); u.w = f2bf(v.w);
    reinterpret_cast<ushort4*>(dst + (size_t)row * 256)[lane] = u;
    #pragma unroll
    for (int o = 32; o; o >>= 1) ss += __shfl_down(ss, o);
    if (lane == 0) nrm[row] = ss;
}

// ---- Phase 2: D = nA[i] + nB[j] - 2*A.B^T, staircase layout, LDS dbuf -----
// grid 3072 x 256 threads (1-D; explicit XCD-contiguous remap inside).
// 128x128 tile/block; wave (wr,wc) does the 64x64 quadrant via 4x4 MFMA
// tiles. K = 8 chunks x 32.
__global__ __launch_bounds__(256) void gemm_lds_kernel(
    const unsigned short* __restrict__ xb, const unsigned short* __restrict__ yb,
    const float* __restrict__ nx, const float* __restrict__ ny,
    unsigned short* __restrict__ Dws) {
    __shared__ short Sb[4][128 * LDA];     // Sb[0..1]=A dbuf, Sb[2..3]=B dbuf
    short (*Ab)[128 * LDA] = Sb;
    short (*Bb)[128 * LDA] = Sb + 2;

    // XCD-contiguous work remap (dispatch round-robin heuristic: XCD = L&7).
    // XCD k owns w in [k*384,(k+1)*384) = 8 batches x {3 p-types x 16 tiles}.
    // Per-XCD distinct input = 8 x (xb[b]+yb[b]) = 4MB = one L2.
    const int L    = blockIdx.x;          // 0..3071
    const int w    = (L & 7) * 384 + (L >> 3);
    const int b    = w / 48;              // batch 0..63
    const int rw   = w % 48;
    const int p    = rw >> 4;             // 0..2
    const int tile = rw & 15;
    const int i0base = (tile & 3) * 128;
    const int j0base = (tile >> 2) * 128;
    const int z = p * 64 + b;             // matrix index for Dws

    const unsigned short* A  = (p == 2) ? yb : xb;
    const unsigned short* Bm = (p == 1) ? xb : yb;
    const float* nA = (p == 2) ? ny : nx;
    const float* nB = (p == 1) ? nx : ny;
    A  += (size_t)b * (512 * 256);
    Bm += (size_t)b * (512 * 256);
    nA += b * 512;
    nB += b * 512;
    unsigned short* Dmat = Dws + (size_t)z * DMAT_ELEMS;

    const int tid  = threadIdx.x;
    const int wave = tid >> 6;
    const int lane = tid & 63;
    const int quad = lane >> 4;
    const int l16  = lane & 15;
    const int wr = wave >> 1, wc = wave & 1;

    // Staging: thread tid handles 16B quarters (row=tid>>2, q=tid&3) of rows
    // [0,64) and [64,128) for both A and B tiles.
    const int srow = tid >> 2;
    const int sq   = tid & 3;
    const short8* gA0 = reinterpret_cast<const short8*>(A  + (size_t)(i0base + srow)      * 256 + sq * 8);
    const short8* gA1 = reinterpret_cast<const short8*>(A  + (size_t)(i0base + srow + 64) * 256 + sq * 8);
    const short8* gB0 = reinterpret_cast<const short8*>(Bm + (size_t)(j0base + srow)      * 256 + sq * 8);
    const short8* gB1 = reinterpret_cast<const short8*>(Bm + (size_t)(j0base + srow + 64) * 256 + sq * 8);
    const int lO0 = srow * LDA + sq * 8;
    const int lO1 = (srow + 64) * LDA + sq * 8;

    // Preload chunk 0 -> buf 0.
    {
        short8 ra0 = gA0[0], ra1 = gA1[0], rb0 = gB0[0], rb1 = gB1[0];
        *reinterpret_cast<short8*>(&Ab[0][lO0]) = ra0;
        *reinterpret_cast<short8*>(&Ab[0][lO1]) = ra1;
        *reinterpret_cast<short8*>(&Bb[0][lO0]) = rb0;
        *reinterpret_cast<short8*>(&Bb[0][lO1]) = rb1;
    }
    __syncthreads();

    floatx4 acc[4][4];
    #pragma unroll
    for (int mt = 0; mt < 4; ++mt)
        #pragma unroll
        for (int nt = 0; nt < 4; ++nt) acc[mt][nt] = (floatx4){0.f, 0.f, 0.f, 0.f};

    #pragma unroll
    for (int c = 0; c < 8; ++c) {
        const int cb = c & 1;
        short8 na0, na1, nb0, nb1;
        if (c < 7) {                      // issue next chunk's global loads
            na0 = gA0[(c + 1) * 4]; na1 = gA1[(c + 1) * 4];
            nb0 = gB0[(c + 1) * 4]; nb1 = gB1[(c + 1) * 4];
        }
        short8 af[4], bfr[4];
        #pragma unroll
        for (int mt = 0; mt < 4; ++mt)
            af[mt] = *reinterpret_cast<const short8*>(&Ab[cb][(wr * 64 + mt * 16 + l16) * LDA + quad * 8]);
        #pragma unroll
        for (int nt = 0; nt < 4; ++nt)
            bfr[nt] = *reinterpret_cast<const short8*>(&Bb[cb][(wc * 64 + nt * 16 + l16) * LDA + quad * 8]);
        #pragma unroll
        for (int mt = 0; mt < 4; ++mt)
            #pragma unroll
            for (int nt = 0; nt < 4; ++nt)
                acc[mt][nt] = __builtin_amdgcn_mfma_f32_16x16x32_bf16(af[mt], bfr[nt], acc[mt][nt], 0, 0, 0);
        if (c < 7) {                      // stage next chunk after MFMA burst
            *reinterpret_cast<short8*>(&Ab[1 - cb][lO0]) = na0;
            *reinterpret_cast<short8*>(&Ab[1 - cb][lO1]) = na1;
            *reinterpret_cast<short8*>(&Bb[1 - cb][lO0]) = nb0;
            *reinterpret_cast<short8*>(&Bb[1 - cb][lO1]) = nb1;
            __syncthreads();
        }
    }

    // ---- Epilogue: LDS transpose -> staircase full-line stores ------------
    // C/D layout col=lane&15, row=quad*4+reg (m89-verified). Each wave owns a
    // private 8KB region (64 cols x 64 rows bf16, col-major, 16B units
    // XOR-swizzled by (col&7)). Wave-local RAW -> no barrier between write
    // and read. One __syncthreads first: regions alias Ab[1]/Bb[*], which
    // other waves still read in chunk 7.
    __syncthreads();
    short* ep = &Sb[0][0] + wave * 4096;
    #pragma unroll
    for (int mt = 0; mt < 4; ++mt) {
        const int ibase = i0base + wr * 64 + mt * 16 + quad * 4;
        const float4 nv = *reinterpret_cast<const float4*>(nA + ibase);
        const int u   = 2 * mt + (quad >> 1);   // logical 16B-unit (0..7)
        const int sub = (quad & 1) * 4;         // short offset within unit
        #pragma unroll
        for (int nt = 0; nt < 4; ++nt) {
            const int cl = nt * 16 + l16;       // local col 0..63
            const float y2 = nB[j0base + wc * 64 + cl];
            ushort4 pk;
            pk.x = f2bf(nv.x + y2 - 2.0f * acc[mt][nt][0]);
            pk.y = f2bf(nv.y + y2 - 2.0f * acc[mt][nt][1]);
            pk.z = f2bf(nv.z + y2 - 2.0f * acc[mt][nt][2]);
            pk.w = f2bf(nv.w + y2 - 2.0f * acc[mt][nt][3]);
            const int pu = u ^ (cl & 7);
            *reinterpret_cast<ushort4*>(ep + cl * 64 + pu * 8 + sub) = pk;
        }
    }
    // Anti-diagonal readout: iteration a0 covers 8 s-rows. Lane (a=l>>3,
    // r=l&7) supplies chunk (cl = s_off - r, unit u = r) -> global chunk
    // (s = Sbase + s_off, t = R0 + r). For each s the 8 r-lanes write
    // (R0+r)*16B consecutive = one FULL aligned 128B line (R0 mult of 8).
    {
        const int R0    = (i0base + wr * 64) >> 3;      // global 8-row index
        const int Sbase = j0base + wc * 64 + R0;
        const int a = lane >> 3, r = lane & 7;
        #pragma unroll
        for (int a0 = 0; a0 < 9; ++a0) {
            const int s_off = a0 * 8 + a;
            const int cl = s_off - r;                   // local col
            if (cl >= 0 && cl < 64) {
                const int pu = r ^ (cl & 7);
                const short8 v = *reinterpret_cast<const short8*>(ep + cl * 64 + pu * 8);
                *reinterpret_cast<short8*>(
                    Dmat + (size_t)(Sbase + s_off) * 512 + (R0 + r) * 8) = v;
            }
        }
    }
}

// ---- Phase 3: one-wave hardmin DTW, reg-dbuf ds_read, min3 chain ----------
// grid 192 x 64 threads (one wave). Lane t owns rows [8t, 8t+8).
// Step s: lane t computes column j = s - t. 576 steps in 72 groups of 8.
// Staircase layout: group load = 8x fully-coalesced 1KB global_load_lds
// (per-lane src base + t*16B; uniform LDS dest + HW lane*16).
// Ring: 6 slots x 8KB; 48 DMAs in flight; vmcnt(40) per group.
// Per group g (steady): vmcnt(40) [g+1's DMA landed] -> ds_read g+1 into
// NEXT regs -> compute g from CUR regs (~180cy, hides ds_read) -> lgkm(0)
// [slot g+1 free] -> issue DMA g+7 into it -> swap bufs. The asm "memory"
// clobbers bracket the ds_reads; compute is register-only and interleaves.
// FAST groups 8..63 (j==0 only in s<=63; j>511 only in s>=512); guarded
// groups 0..7 and 64..71.

#define SLOT6(x) ((x) % 6)

#define DTW_ISSUE(gidx, slot)                                                 \
    {                                                                         \
        int s8_ = (gidx) * 8;                                                 \
        if (s8_ > 568) s8_ = 568;   /* keep s in [0,575] (pad rows) */        \
        const unsigned short* gsrc_ = Dmat + (size_t)s8_ * 512 + t * 8;       \
        _Pragma("unroll")                                                     \
        for (int k = 0; k < 8; ++k)                                           \
            gload16(gsrc_ + k * 512, (void*)&ring[((slot) * 8 + k) * 64]);    \
    }

#define DTW_READ(buf, slot)                                                   \
    _Pragma("unroll")                                                         \
    for (int k = 0; k < 8; ++k) buf[k] = ring[((slot) * 8 + k) * 64 + t];

#define DTW_UNPACK(buf, k, d)                                                 \
    d[0] = bf2f_lo(buf[k].x); d[1] = bf2f_hi(buf[k].x);                       \
    d[2] = bf2f_lo(buf[k].y); d[3] = bf2f_hi(buf[k].y);                       \
    d[4] = bf2f_lo(buf[k].z); d[5] = bf2f_hi(buf[k].z);                       \
    d[6] = bf2f_lo(buf[k].w); d[7] = bf2f_hi(buf[k].w);

// min3-fused cell chain: c_r = d_r + min3(prev[r-1], prev[r], c_{r-1}).
#define DTW_CELLS(d, u0, u1)                                                  \
    {                                                                         \
        float c = d[0] + fminf(fminf(u0, prev[0]), u1);                       \
        float nv[8]; nv[0] = c;                                               \
        _Pragma("unroll")                                                     \
        for (int r = 1; r < 8; ++r) {                                         \
            c = d[r] + fminf(fminf(prev[r - 1], prev[r]), c);                 \
            nv[r] = c;                                                        \
        }                                                                     \
        _Pragma("unroll")                                                     \
        for (int r = 0; r < 8; ++r) prev[r] = nv[r];                          \
        bot = c;                                                              \
    }

// Guarded step (ramp-up / ramp-down): full j-range + j==0 handling.
#define DTW_COMPG(buf, gidx)                                                  \
    {                                                                         \
        const int s0_ = (gidx) * 8;                                           \
        _Pragma("unroll")                                                     \
        for (int k = 0; k < 8; ++k) {                                         \
            const int j = s0_ + k - t;                                        \
            const float recv = dpp_shr1(bot);                                 \
            const float u1 = (t == 0) ? SDTW_BIG : recv;                      \
            float u0 = u1s;                                                   \
            if (j == 0) u0 = (t == 0) ? 0.0f : SDTW_BIG;                      \
            u1s = u1;                                                         \
            if (j >= 0 && j < 512) {                                          \
                float d[8];                                                   \
                DTW_UNPACK(buf, k, d)                                         \
                DTW_CELLS(d, u0, u1)                                          \
            }                                                                 \
        }                                                                     \
    }

// Fast step (steady state, s in [64,512)): all lanes valid, j!=0.
#define DTW_COMPF(buf, gidx)                                                  \
    {                                                                         \
        _Pragma("unroll")                                                     \
        for (int k = 0; k < 8; ++k) {                                         \
            const float recv = dpp_shr1(bot);                                 \
            const float u1 = (t == 0) ? SDTW_BIG : recv;                      \
            const float u0 = u1s;                                             \
            u1s = u1;                                                         \
            float d[8];                                                       \
            DTW_UNPACK(buf, k, d)                                             \
            DTW_CELLS(d, u0, u1)                                              \
        }                                                                     \
    }

// Pipelined step for group g: BC holds g's data (drained), BN receives g+1.
#define DTW_STEP(gidx, BC, BN, COMP)                                          \
    {                                                                         \
        asm volatile("s_waitcnt vmcnt(40)" ::: "memory");                     \
        DTW_READ(BN, SLOT6((gidx) + 1))                                       \
        COMP(BC, gidx)                                                        \
        asm volatile("s_waitcnt lgkmcnt(0)" ::: "memory");                    \
        DTW_ISSUE((gidx) + 7, SLOT6((gidx) + 1))                              \
    }

#define DTW_PAIR(g, COMP)                                                     \
    DTW_STEP(g, bA, bB, COMP)                                                 \
    DTW_STEP((g) + 1, bB, bA, COMP)

__global__ __launch_bounds__(64) void dtw_wave_kernel(
    const unsigned short* __restrict__ Dws, float* __restrict__ out) {
    __shared__ uint4 ring[6 * 8 * 64];   // 48KB: 6 slots x (8 s-rows x 1KB)
    const int z = blockIdx.x;            // p*64 + b
    const int p = z >> 6;
    const int b = z & 63;
    const unsigned short* Dmat = Dws + (size_t)z * DMAT_ELEMS;
    const int t = threadIdx.x;           // lane 0..63

    float prev[8];                        // R[8t+r, j-1]
    #pragma unroll
    for (int r = 0; r < 8; ++r) prev[r] = SDTW_BIG;
    float bot = SDTW_BIG;                 // bottom-row value after last step
    float u1s = SDTW_BIG;                 // post-override u1 of last step

    uint4 bA[8], bB[8];

    // Prologue: fill the ring (groups 0..5, 48 DMAs), pull group 0 into bA,
    // reissue slot 0 with group 6 (back to 48 outstanding).
    DTW_ISSUE(0, 0)
    DTW_ISSUE(1, 1)
    DTW_ISSUE(2, 2)
    DTW_ISSUE(3, 3)
    DTW_ISSUE(4, 4)
    DTW_ISSUE(5, 5)
    asm volatile("s_waitcnt vmcnt(40)" ::: "memory");
    DTW_READ(bA, 0)
    asm volatile("s_waitcnt lgkmcnt(0)" ::: "memory");
    DTW_ISSUE(6, 0)

    // Guarded ramp-up: groups 0..7 (j==0 cases live in s<=63).
    DTW_PAIR(0, DTW_COMPG)
    DTW_PAIR(2, DTW_COMPG)
    DTW_PAIR(4, DTW_COMPG)
    DTW_PAIR(6, DTW_COMPG)
    // Fast: groups 8..61 in 9 blocks of 6 (slot constants fold: g=8+6*blk).
    for (int blk = 0; blk < 9; ++blk) {
        const int g = 8 + blk * 6;
        DTW_STEP(g + 0, bA, bB, DTW_COMPF)
        DTW_STEP(g + 1, bB, bA, DTW_COMPF)
        DTW_STEP(g + 2, bA, bB, DTW_COMPF)
        DTW_STEP(g + 3, bB, bA, DTW_COMPF)
        DTW_STEP(g + 4, bA, bB, DTW_COMPF)
        DTW_STEP(g + 5, bB, bA, DTW_COMPF)
    }
    // Fast tail: groups 62..63.
    DTW_PAIR(62, DTW_COMPF)
    // Guarded ramp-down: groups 64..70 pipelined (issue side clamps to 568),
    // group 71 compute-only from bB (step 70 read it).
    DTW_PAIR(64, DTW_COMPG)
    DTW_PAIR(66, DTW_COMPG)
    DTW_PAIR(68, DTW_COMPG)
    DTW_STEP(70, bA, bB, DTW_COMPG)
    DTW_COMPG(bB, 71)

    asm volatile("s_waitcnt vmcnt(0)" ::: "memory");  // drain tail DMAs

    if (t == 63) {                // bot == R[511,511]
        const float coef = (p == 0) ? 1.0f : -0.5f;
        atomicAdd(&out[b], coef * bot);
    }
}

extern "C" void kernel_launch(void* const* d_in, const int* in_sizes, int n_in,
                              void* d_out, int out_size, void* d_ws, size_t ws_size,
                              hipStream_t stream) {
    const float* x = (const float*)d_in[0];
    const float* y = (const float*)d_in[1];
    float* out = (float*)d_out;
    char* ws = (char*)d_ws;

    // ws layout (bytes):
    //   [0, 113246208)              D bf16 staircase, 192 x 294912 elems
    //   [113246208, 130023424)      xb bf16
    //   [130023424, 146800640)      yb bf16
    //   [146800640, 146931712)      nx fp32
    //   [146931712, 147062784)      ny fp32
    unsigned short* Dws = (unsigned short*)ws;
    unsigned short* xb  = (unsigned short*)(ws + 113246208);
    unsigned short* yb  = (unsigned short*)(ws + 130023424);
    float* nx = (float*)(ws + 146800640);
    float* ny = (float*)(ws + 146931712);

    hipMemsetAsync(d_out, 0, 64 * sizeof(float), stream);
    convert_norm_kernel<<<dim3(8192, 2), 256, 0, stream>>>(x, y, xb, yb, nx, ny);
    gemm_lds_kernel<<<3072, 256, 0, stream>>>(xb, yb, nx, ny, Dws);
    dtw_wave_kernel<<<192, 64, 0, stream>>>(Dws, out);
}

// Round 11
// 194.899 us; speedup vs baseline: 1.0190x; 1.0190x over previous
//
#include <hip/hip_runtime.h>
#include <hip/hip_bf16.h>

// DTWLoss: out[b] = softDTW(sqdist(x,y)) - 0.5*(softDTW(sqdist(x,x)) + softDTW(sqdist(y,y)))
// B=64, N=M=512, F=256, gamma=0.1, BIG=1e8. Output: 64 fp32.
//
// Phase 1: convert x,y to bf16 + fp32 row norms.
// Phase 2: 192 batched MFMA GEMMs, 128x128 tile, LDS dbuf. D stored bf16 in
//          SKEW-2 STAIRCASE: chunk (rows 8q..8q+7, col j) at row s2 = j+2q,
//          16B at (s2*64+q)*8 elems. Epilogue: LDS transpose + anti-diagonal
//          readout (cl = s_off - 2r) -> full 128B-line stores. XCD-contiguous
//          work remap (gemm <54us since R7).
// Phase 3: wavefront DTW (hardmin; |softmin-min|<=gamma*ln3/cell, total <=112
//          vs 5242.88 threshold). R10 reg-dbuf REGRESSED (62us, VALUBusy
//          7.8%): R9's read->drain->compute was already well-scheduled;
//          reverted. R11: TWO COLUMNS PER STEP. Lane t owns rows 8t..8t+7,
//          super-step S computes cols jA=2(S-t), jB=jA+1 (skew-2 diagonal).
//          Deps: lane t needs lane t-1 bottoms from steps S-1/S-2 only ->
//          2 dpp/super-step, state (pL,pA,pB), pL'=pB. 319 super-steps vs
//          576: issue AND chain per column nearly halve (B-chain interleaves
//          into A-chain stall slots). Ring/DMA identical to R9 (8x1KB rows
//          per group, 6 slots, vmcnt(40)); guards collapse to 0<=jA<=510
//          (jA==0 fix folded into pL init).

#define SDTW_BIG   1e8f
#define LDA 40        // LDS row stride in shorts (32 + 8 pad)
#define DROWS 640     // skew-2 staircase rows (638 used + pad to 80 groups)
#define DMAT_ELEMS (DROWS * 512)   // 327680 elems = 655360 B per matrix

typedef __attribute__((ext_vector_type(8))) short short8;   // 8 bf16
typedef __attribute__((ext_vector_type(4))) float floatx4;  // mfma acc

__device__ __forceinline__ unsigned short f2bf(float f) {
    __hip_bfloat16 h = __float2bfloat16(f);
    return *reinterpret_cast<unsigned short*>(&h);
}
__device__ __forceinline__ float bf2f_lo(unsigned int u) {
    return __uint_as_float(u << 16);
}
__device__ __forceinline__ float bf2f_hi(unsigned int u) {
    return __uint_as_float(u & 0xFFFF0000u);
}

// shfl_up(x,1) as DPP wave_shr:1 (0x138): lane i <- lane i-1, pure VALU.
// Lane 0 keeps old (=x); caller overrides t==0.
__device__ __forceinline__ float dpp_shr1(float x) {
    const int xi = __float_as_int(x);
    const int r = __builtin_amdgcn_update_dpp(xi, xi, 0x138, 0xf, 0xf, false);
    return __int_as_float(r);
}

// async global->LDS DMA, 16B per lane. LDS dest is wave-uniform base; HW adds
// lane*16. Global src is PER-LANE (each lane's own VGPR address).
__device__ __forceinline__ void gload16(const unsigned short* g, void* l) {
    __builtin_amdgcn_global_load_lds(
        (const __attribute__((address_space(1))) void*)g,
        (__attribute__((address_space(3))) void*)l, 16, 0, 0);
}

// ---- Phase 1: fp32 -> bf16 + row sum-of-squares (fp32) --------------------
__global__ __launch_bounds__(256) void convert_norm_kernel(
    const float* __restrict__ x, const float* __restrict__ y,
    unsigned short* __restrict__ xb, unsigned short* __restrict__ yb,
    float* __restrict__ nx, float* __restrict__ ny) {
    const float* src = blockIdx.y ? y : x;
    unsigned short* dst = blockIdx.y ? yb : xb;
    float* nrm = blockIdx.y ? ny : nx;
    const int wave = threadIdx.x >> 6;
    const int lane = threadIdx.x & 63;
    const int row  = blockIdx.x * 4 + wave;          // 0..32767
    const float4 v = reinterpret_cast<const float4*>(src + (size_t)row * 256)[lane];
    float ss = v.x * v.x + v.y * v.y + v.z * v.z + v.w * v.w;
    ushort4 u;
    u.x = f2bf(v.x); u.y = f2bf(v.y); u.z = f2bf(v.z); u.w = f2bf(v.w);
    reinterpret_cast<ushort4*>(dst + (size_t)row * 256)[lane] = u;
    #pragma unroll
    for (int o = 32; o; o >>= 1) ss += __shfl_down(ss, o);
    if (lane == 0) nrm[row] = ss;
}

// ---- Phase 2: D = nA[i] + nB[j] - 2*A.B^T, skew-2 staircase, LDS dbuf -----
// grid 3072 x 256 threads (1-D; explicit XCD-contiguous remap inside).
// 128x128 tile/block; wave (wr,wc) does the 64x64 quadrant via 4x4 MFMA
// tiles. K = 8 chunks x 32.
__global__ __launch_bounds__(256) void gemm_lds_kernel(
    const unsigned short* __restrict__ xb, const unsigned short* __restrict__ yb,
    const float* __restrict__ nx, const float* __restrict__ ny,
    unsigned short* __restrict__ Dws) {
    __shared__ short Sb[4][128 * LDA];     // Sb[0..1]=A dbuf, Sb[2..3]=B dbuf
    short (*Ab)[128 * LDA] = Sb;
    short (*Bb)[128 * LDA] = Sb + 2;

    // XCD-contiguous work remap (dispatch round-robin heuristic: XCD = L&7).
    // XCD k owns w in [k*384,(k+1)*384) = 8 batches x {3 p-types x 16 tiles}.
    const int L    = blockIdx.x;          // 0..3071
    const int w    = (L & 7) * 384 + (L >> 3);
    const int b    = w / 48;              // batch 0..63
    const int rw   = w % 48;
    const int p    = rw >> 4;             // 0..2
    const int tile = rw & 15;
    const int i0base = (tile & 3) * 128;
    const int j0base = (tile >> 2) * 128;
    const int z = p * 64 + b;             // matrix index for Dws

    const unsigned short* A  = (p == 2) ? yb : xb;
    const unsigned short* Bm = (p == 1) ? xb : yb;
    const float* nA = (p == 2) ? ny : nx;
    const float* nB = (p == 1) ? nx : ny;
    A  += (size_t)b * (512 * 256);
    Bm += (size_t)b * (512 * 256);
    nA += b * 512;
    nB += b * 512;
    unsigned short* Dmat = Dws + (size_t)z * DMAT_ELEMS;

    const int tid  = threadIdx.x;
    const int wave = tid >> 6;
    const int lane = tid & 63;
    const int quad = lane >> 4;
    const int l16  = lane & 15;
    const int wr = wave >> 1, wc = wave & 1;

    // Staging: thread tid handles 16B quarters (row=tid>>2, q=tid&3) of rows
    // [0,64) and [64,128) for both A and B tiles.
    const int srow = tid >> 2;
    const int sq   = tid & 3;
    const short8* gA0 = reinterpret_cast<const short8*>(A  + (size_t)(i0base + srow)      * 256 + sq * 8);
    const short8* gA1 = reinterpret_cast<const short8*>(A  + (size_t)(i0base + srow + 64) * 256 + sq * 8);
    const short8* gB0 = reinterpret_cast<const short8*>(Bm + (size_t)(j0base + srow)      * 256 + sq * 8);
    const short8* gB1 = reinterpret_cast<const short8*>(Bm + (size_t)(j0base + srow + 64) * 256 + sq * 8);
    const int lO0 = srow * LDA + sq * 8;
    const int lO1 = (srow + 64) * LDA + sq * 8;

    // Preload chunk 0 -> buf 0.
    {
        short8 ra0 = gA0[0], ra1 = gA1[0], rb0 = gB0[0], rb1 = gB1[0];
        *reinterpret_cast<short8*>(&Ab[0][lO0]) = ra0;
        *reinterpret_cast<short8*>(&Ab[0][lO1]) = ra1;
        *reinterpret_cast<short8*>(&Bb[0][lO0]) = rb0;
        *reinterpret_cast<short8*>(&Bb[0][lO1]) = rb1;
    }
    __syncthreads();

    floatx4 acc[4][4];
    #pragma unroll
    for (int mt = 0; mt < 4; ++mt)
        #pragma unroll
        for (int nt = 0; nt < 4; ++nt) acc[mt][nt] = (floatx4){0.f, 0.f, 0.f, 0.f};

    #pragma unroll
    for (int c = 0; c < 8; ++c) {
        const int cb = c & 1;
        short8 na0, na1, nb0, nb1;
        if (c < 7) {                      // issue next chunk's global loads
            na0 = gA0[(c + 1) * 4]; na1 = gA1[(c + 1) * 4];
            nb0 = gB0[(c + 1) * 4]; nb1 = gB1[(c + 1) * 4];
        }
        short8 af[4], bfr[4];
        #pragma unroll
        for (int mt = 0; mt < 4; ++mt)
            af[mt] = *reinterpret_cast<const short8*>(&Ab[cb][(wr * 64 + mt * 16 + l16) * LDA + quad * 8]);
        #pragma unroll
        for (int nt = 0; nt < 4; ++nt)
            bfr[nt] = *reinterpret_cast<const short8*>(&Bb[cb][(wc * 64 + nt * 16 + l16) * LDA + quad * 8]);
        #pragma unroll
        for (int mt = 0; mt < 4; ++mt)
            #pragma unroll
            for (int nt = 0; nt < 4; ++nt)
                acc[mt][nt] = __builtin_amdgcn_mfma_f32_16x16x32_bf16(af[mt], bfr[nt], acc[mt][nt], 0, 0, 0);
        if (c < 7) {                      // stage next chunk after MFMA burst
            *reinterpret_cast<short8*>(&Ab[1 - cb][lO0]) = na0;
            *reinterpret_cast<short8*>(&Ab[1 - cb][lO1]) = na1;
            *reinterpret_cast<short8*>(&Bb[1 - cb][lO0]) = nb0;
            *reinterpret_cast<short8*>(&Bb[1 - cb][lO1]) = nb1;
            __syncthreads();
        }
    }

    // ---- Epilogue: LDS transpose -> skew-2 staircase full-line stores -----
    // C/D layout col=lane&15, row=quad*4+reg (m89-verified). Each wave owns a
    // private 8KB region (64 cols x 64 rows bf16, col-major, 16B units
    // XOR-swizzled by (col&7)). Wave-local RAW -> no barrier between write
    // and read. One __syncthreads first: regions alias Ab[1]/Bb[*], which
    // other waves still read in chunk 7.
    __syncthreads();
    short* ep = &Sb[0][0] + wave * 4096;
    #pragma unroll
    for (int mt = 0; mt < 4; ++mt) {
        const int ibase = i0base + wr * 64 + mt * 16 + quad * 4;
        const float4 nv = *reinterpret_cast<const float4*>(nA + ibase);
        const int u   = 2 * mt + (quad >> 1);   // logical 16B-unit (0..7)
        const int sub = (quad & 1) * 4;         // short offset within unit
        #pragma unroll
        for (int nt = 0; nt < 4; ++nt) {
            const int cl = nt * 16 + l16;       // local col 0..63
            const float y2 = nB[j0base + wc * 64 + cl];
            ushort4 pk;
            pk.x = f2bf(nv.x + y2 - 2.0f * acc[mt][nt][0]);
            pk.y = f2bf(nv.y + y2 - 2.0f * acc[mt][nt][1]);
            pk.z = f2bf(nv.z + y2 - 2.0f * acc[mt][nt][2]);
            pk.w = f2bf(nv.w + y2 - 2.0f * acc[mt][nt][3]);
            const int pu = u ^ (cl & 7);
            *reinterpret_cast<ushort4*>(ep + cl * 64 + pu * 8 + sub) = pk;
        }
    }
    // Anti-diagonal readout (skew-2): lane (a=l>>3, r=l&7) supplies unit r of
    // local col cl = s_off - 2r (s_off = a0*8 + a) -> global chunk q = R0+r,
    // col j = J0+cl, row s2 = j + 2q = S2base + s_off, S2base = J0 + 2*R0.
    // For each s2-row the 8 r-lanes write (R0+r)*16B consecutive = one FULL
    // aligned 128B line (R0 mult of 8). s_off range 0..77 -> a0 0..9.
    {
        const int R0     = (i0base + wr * 64) >> 3;     // global 8-row index
        const int S2base = j0base + wc * 64 + 2 * R0;
        const int a = lane >> 3, r = lane & 7;
        #pragma unroll
        for (int a0 = 0; a0 < 10; ++a0) {
            const int s_off = a0 * 8 + a;
            const int cl = s_off - 2 * r;               // local col
            if (cl >= 0 && cl < 64) {
                const int pu = r ^ (cl & 7);
                const short8 v = *reinterpret_cast<const short8*>(ep + cl * 64 + pu * 8);
                *reinterpret_cast<short8*>(
                    Dmat + (size_t)(S2base + s_off) * 512 + (R0 + r) * 8) = v;
            }
        }
    }
}

// ---- Phase 3: one-wave hardmin DTW, 2-col super-steps, skew-2 -------------
// grid 192 x 64 threads (one wave). Lane t owns rows [8t, 8t+8).
// Super-step S: lane t computes cols jA=2(S-t), jB=jA+1 (valid iff
// 0<=jA<=510; A/B valid together). 319 super-steps in 80 groups of 4.
// Group g reads s2-rows 8g..8g+7 (super-step 4g+m uses rows 2m, 2m+1 of the
// slot); each row = 1KB contiguous -> 8x gload16/group, ring 6 slots x 8KB,
// 48 DMAs in flight, vmcnt(40) per group (R9 structure verbatim).
// Cross-lane state: pA=R[8t-1,jA], pB=R[8t-1,jB], pL=R[8t-1,jA-1].
// Update after step: pL'=pB; pA'=dpp(botA); pB'=dpp(botB) (lane0 -> BIG).
// Init pL = (t==0 ? 0 : BIG) handles the DP origin (jA==0 at S=t).

#define DTW_ISSUE(gidx, slot)                                                 \
    {                                                                         \
        int s8_ = (gidx) * 8;                                                 \
        if (s8_ > 632) s8_ = 632;   /* keep rows in [0,640) (pad rows) */     \
        const unsigned short* gsrc_ = Dmat + (size_t)s8_ * 512 + t * 8;       \
        _Pragma("unroll")                                                     \
        for (int k = 0; k < 8; ++k)                                           \
            gload16(gsrc_ + k * 512, (void*)&ring[((slot) * 8 + k) * 64]);    \
    }

#define DTW_UNPACK1(buf, d)                                                   \
    d[0] = bf2f_lo(buf.x); d[1] = bf2f_hi(buf.x);                             \
    d[2] = bf2f_lo(buf.y); d[3] = bf2f_hi(buf.y);                             \
    d[4] = bf2f_lo(buf.z); d[5] = bf2f_hi(buf.z);                             \
    d[6] = bf2f_lo(buf.w); d[7] = bf2f_hi(buf.w);

// Core 2-col cell block (no guards). Col A: diag/top from (pL,pA), left from
// prev[]. Col B: diag/top from (pA,pB)/chain, left from col A. min3-fused.
#define DTW_CELLS2(ca, cb)                                                    \
    {                                                                         \
        float dA[8], dB[8];                                                   \
        DTW_UNPACK1(ca, dA)                                                   \
        DTW_UNPACK1(cb, dB)                                                   \
        float cA[8], cB[8];                                                   \
        cA[0] = dA[0] + fminf(fminf(pL, pA), prev[0]);                        \
        _Pragma("unroll")                                                     \
        for (int r = 1; r < 8; ++r)                                           \
            cA[r] = dA[r] + fminf(fminf(prev[r - 1], prev[r]), cA[r - 1]);    \
        cB[0] = dB[0] + fminf(fminf(pA, pB), cA[0]);                          \
        _Pragma("unroll")                                                     \
        for (int r = 1; r < 8; ++r)                                           \
            cB[r] = dB[r] + fminf(fminf(cA[r - 1], cB[r - 1]), cA[r]);        \
        _Pragma("unroll")                                                     \
        for (int r = 0; r < 8; ++r) prev[r] = cB[r];                          \
        botA = cA[7]; botB = cB[7];                                           \
    }

// Cross-lane handoff (all lanes, every super-step).
#define DTW_HANDOFF                                                           \
    {                                                                         \
        const float rA_ = dpp_shr1(botA);                                     \
        const float rB_ = dpp_shr1(botB);                                     \
        pL = pB;                                                              \
        pA = (t == 0) ? SDTW_BIG : rA_;                                       \
        pB = (t == 0) ? SDTW_BIG : rB_;                                       \
    }

// Fast super-step (all lanes valid).
#define DTW_SSF(ca, cb, Sv)                                                   \
    {                                                                         \
        DTW_CELLS2(ca, cb)                                                    \
        DTW_HANDOFF                                                           \
    }

// Guarded super-step (ramps): compute only if 0 <= jA <= 510.
#define DTW_SSG(ca, cb, Sv)                                                   \
    {                                                                         \
        const int jA_ = 2 * ((Sv) - t);                                       \
        if (jA_ >= 0 && jA_ <= 510) {                                         \
            DTW_CELLS2(ca, cb)                                                \
        }                                                                     \
        DTW_HANDOFF                                                           \
    }

// One group (R9 structure): wait oldest DMA group -> ds_read slot -> drain
// lgkm (regs hold data; slot free) -> issue DMA g+6 -> 4 super-steps.
#define DTW_GROUP2(g, slot, SS)                                               \
    {                                                                         \
        asm volatile("s_waitcnt vmcnt(40)" ::: "memory");                     \
        _Pragma("unroll")                                                     \
        for (int k = 0; k < 8; ++k) cur[k] = ring[((slot) * 8 + k) * 64 + t]; \
        asm volatile("s_waitcnt lgkmcnt(0)" ::: "memory");                    \
        DTW_ISSUE((g) + 6, slot)                                              \
        SS(cur[0], cur[1], 4 * (g) + 0)                                       \
        SS(cur[2], cur[3], 4 * (g) + 1)                                       \
        SS(cur[4], cur[5], 4 * (g) + 2)                                       \
        SS(cur[6], cur[7], 4 * (g) + 3)                                       \
    }

__global__ __launch_bounds__(64) void dtw_wave_kernel(
    const unsigned short* __restrict__ Dws, float* __restrict__ out) {
    __shared__ uint4 ring[6 * 8 * 64];   // 48KB: 6 slots x (8 s2-rows x 1KB)
    const int z = blockIdx.x;            // p*64 + b
    const int p = z >> 6;
    const int b = z & 63;
    const unsigned short* Dmat = Dws + (size_t)z * DMAT_ELEMS;
    const int t = threadIdx.x;           // lane 0..63

    float prev[8];                        // R[8t+r, jB] of last super-step
    #pragma unroll
    for (int r = 0; r < 8; ++r) prev[r] = SDTW_BIG;
    float botA = SDTW_BIG, botB = SDTW_BIG;
    float pA = SDTW_BIG, pB = SDTW_BIG;
    float pL = (t == 0) ? 0.0f : SDTW_BIG;   // DP origin: R[-1,-1]=0 for lane0

    uint4 cur[8];

    // Prologue: fill the ring (groups 0..5, 48 DMA loads in flight).
    DTW_ISSUE(0, 0)
    DTW_ISSUE(1, 1)
    DTW_ISSUE(2, 2)
    DTW_ISSUE(3, 3)
    DTW_ISSUE(4, 4)
    DTW_ISSUE(5, 5)

    // Guarded ramp-up: groups 0..15 (S 0..63; lanes activate at S=t).
    for (int g = 0; g < 16; ++g) {
        DTW_GROUP2(g, g % 6, DTW_SSG)
    }
    // Fast: groups 16..63 (S 64..255: all lanes valid). Slots (16+i)%6 fold
    // per position: 4,5,0,1,2,3.
    for (int blk = 0; blk < 8; ++blk) {
        const int g = 16 + blk * 6;
        DTW_GROUP2(g + 0, 4, DTW_SSF)
        DTW_GROUP2(g + 1, 5, DTW_SSF)
        DTW_GROUP2(g + 2, 0, DTW_SSF)
        DTW_GROUP2(g + 3, 1, DTW_SSF)
        DTW_GROUP2(g + 4, 2, DTW_SSF)
        DTW_GROUP2(g + 5, 3, DTW_SSF)
    }
    // Guarded ramp-down: groups 64..79 (S 256..319; lanes retire at
    // S=256+t; issue side clamps to row 632).
    for (int g = 64; g < 80; ++g) {
        DTW_GROUP2(g, g % 6, DTW_SSG)
    }

    asm volatile("s_waitcnt vmcnt(0)" ::: "memory");  // drain tail DMAs

    if (t == 63) {                // botB == R[511,511] (S=318: jB=511)
        const float coef = (p == 0) ? 1.0f : -0.5f;
        atomicAdd(&out[b], coef * botB);
    }
}

extern "C" void kernel_launch(void* const* d_in, const int* in_sizes, int n_in,
                              void* d_out, int out_size, void* d_ws, size_t ws_size,
                              hipStream_t stream) {
    const float* x = (const float*)d_in[0];
    const float* y = (const float*)d_in[1];
    float* out = (float*)d_out;
    char* ws = (char*)d_ws;

    // ws layout (bytes):
    //   [0, 125829120)              D bf16 skew-2 staircase, 192 x 327680
    //   [125829120, 142606336)      xb bf16
    //   [142606336, 159383552)      yb bf16
    //   [159383552, 159514624)      nx fp32
    //   [159514624, 159645696)      ny fp32
    unsigned short* Dws = (unsigned short*)ws;
    unsigned short* xb  = (unsigned short*)(ws + 125829120);
    unsigned short* yb  = (unsigned short*)(ws + 142606336);
    float* nx = (float*)(ws + 159383552);
    float* ny = (float*)(ws + 159514624);

    hipMemsetAsync(d_out, 0, 64 * sizeof(float), stream);
    convert_norm_kernel<<<dim3(8192, 2), 256, 0, stream>>>(x, y, xb, yb, nx, ny);
    gemm_lds_kernel<<<3072, 256, 0, stream>>>(xb, yb, nx, ny, Dws);
    dtw_wave_kernel<<<192, 64, 0, stream>>>(Dws, out);
}

// Round 13
// 185.147 us; speedup vs baseline: 1.0727x; 1.0527x over previous
//
#include <hip/hip_runtime.h>
#include <hip/hip_bf16.h>

// DTWLoss: out[b] = softDTW(sqdist(x,y)) - 0.5*(softDTW(sqdist(x,x)) + softDTW(sqdist(y,y)))
// B=64, N=M=512, F=256, gamma=0.1, BIG=1e8. Output: 64 fp32.
//
// Phase 1: convert x,y to bf16 + fp32 row norms.
// Phase 2: 192 batched MFMA GEMMs, 128x128 tile, LDS dbuf. D stored bf16 in
//          SKEW-2 STAIRCASE: chunk (rows 8q..8q+7, col j) at row s2 = j+2q,
//          16B at (s2*64+q)*8 elems. Epilogue: LDS transpose + anti-diagonal
//          readout (cl = s_off - 2r) -> full 128B-line stores. XCD-contiguous
//          work remap (gemm <54us since R7). [R11-verified]
// Phase 3: wavefront DTW (hardmin; |softmin-min|<=gamma*ln3/cell, total <=112
//          vs 5242.88 threshold). 2-col super-steps (R11-verified math).
//          R11 post-mortem: compute off critical path; 54us ~= 640
//          global_load_lds x ~200cy -> per-wave LDS-DMA serializes.
//          R12 (hand-asm direct loads + manual vmcnt) FAILED correctness
//          (absmax 2.6e5) -- opaque asm hazard. R13: same theory, safe
//          mechanism: PLAIN C++ loads (compiler tracks vmcnt exactly,
//          inserts counted waits, handles spills) + sched_barrier(0)
//          fences to pin load placement (R1's sink failure can't recur).
//          Depth-2 reg pipeline (B0/B1, 64 VGPR): group g's loads issued
//          2 PROCs (~800cy) before use; D is L2/L3-warm (~200-400cy).

#define SDTW_BIG   1e8f
#define LDA 40        // LDS row stride in shorts (32 + 8 pad)
#define DROWS 640     // skew-2 staircase rows (638 used + pad to 80 groups)
#define DMAT_ELEMS (DROWS * 512)   // 327680 elems = 655360 B per matrix

typedef __attribute__((ext_vector_type(8))) short short8;   // 8 bf16
typedef __attribute__((ext_vector_type(4))) float floatx4;  // mfma acc

__device__ __forceinline__ unsigned short f2bf(float f) {
    __hip_bfloat16 h = __float2bfloat16(f);
    return *reinterpret_cast<unsigned short*>(&h);
}
__device__ __forceinline__ float bf2f_lo(unsigned int u) {
    return __uint_as_float(u << 16);
}
__device__ __forceinline__ float bf2f_hi(unsigned int u) {
    return __uint_as_float(u & 0xFFFF0000u);
}

// shfl_up(x,1) as DPP wave_shr:1 (0x138): lane i <- lane i-1, pure VALU.
// Lane 0 keeps old (=x); caller overrides t==0.
__device__ __forceinline__ float dpp_shr1(float x) {
    const int xi = __float_as_int(x);
    const int r = __builtin_amdgcn_update_dpp(xi, xi, 0x138, 0xf, 0xf, false);
    return __int_as_float(r);
}

// ---- Phase 1: fp32 -> bf16 + row sum-of-squares (fp32) --------------------
__global__ __launch_bounds__(256) void convert_norm_kernel(
    const float* __restrict__ x, const float* __restrict__ y,
    unsigned short* __restrict__ xb, unsigned short* __restrict__ yb,
    float* __restrict__ nx, float* __restrict__ ny) {
    const float* src = blockIdx.y ? y : x;
    unsigned short* dst = blockIdx.y ? yb : xb;
    float* nrm = blockIdx.y ? ny : nx;
    const int wave = threadIdx.x >> 6;
    const int lane = threadIdx.x & 63;
    const int row  = blockIdx.x * 4 + wave;          // 0..32767
    const float4 v = reinterpret_cast<const float4*>(src + (size_t)row * 256)[lane];
    float ss = v.x * v.x + v.y * v.y + v.z * v.z + v.w * v.w;
    ushort4 u;
    u.x = f2bf(v.x); u.y = f2bf(v.y); u.z = f2bf(v.z); u.w = f2bf(v.w);
    reinterpret_cast<ushort4*>(dst + (size_t)row * 256)[lane] = u;
    #pragma unroll
    for (int o = 32; o; o >>= 1) ss += __shfl_down(ss, o);
    if (lane == 0) nrm[row] = ss;
}

// ---- Phase 2: D = nA[i] + nB[j] - 2*A.B^T, skew-2 staircase, LDS dbuf -----
// grid 3072 x 256 threads (1-D; explicit XCD-contiguous remap inside).
// 128x128 tile/block; wave (wr,wc) does the 64x64 quadrant via 4x4 MFMA
// tiles. K = 8 chunks x 32.
__global__ __launch_bounds__(256) void gemm_lds_kernel(
    const unsigned short* __restrict__ xb, const unsigned short* __restrict__ yb,
    const float* __restrict__ nx, const float* __restrict__ ny,
    unsigned short* __restrict__ Dws) {
    __shared__ short Sb[4][128 * LDA];     // Sb[0..1]=A dbuf, Sb[2..3]=B dbuf
    short (*Ab)[128 * LDA] = Sb;
    short (*Bb)[128 * LDA] = Sb + 2;

    // XCD-contiguous work remap (dispatch round-robin heuristic: XCD = L&7).
    // XCD k owns w in [k*384,(k+1)*384) = 8 batches x {3 p-types x 16 tiles}.
    const int L    = blockIdx.x;          // 0..3071
    const int w    = (L & 7) * 384 + (L >> 3);
    const int b    = w / 48;              // batch 0..63
    const int rw   = w % 48;
    const int p    = rw >> 4;             // 0..2
    const int tile = rw & 15;
    const int i0base = (tile & 3) * 128;
    const int j0base = (tile >> 2) * 128;
    const int z = p * 64 + b;             // matrix index for Dws

    const unsigned short* A  = (p == 2) ? yb : xb;
    const unsigned short* Bm = (p == 1) ? xb : yb;
    const float* nA = (p == 2) ? ny : nx;
    const float* nB = (p == 1) ? nx : ny;
    A  += (size_t)b * (512 * 256);
    Bm += (size_t)b * (512 * 256);
    nA += b * 512;
    nB += b * 512;
    unsigned short* Dmat = Dws + (size_t)z * DMAT_ELEMS;

    const int tid  = threadIdx.x;
    const int wave = tid >> 6;
    const int lane = tid & 63;
    const int quad = lane >> 4;
    const int l16  = lane & 15;
    const int wr = wave >> 1, wc = wave & 1;

    // Staging: thread tid handles 16B quarters (row=tid>>2, q=tid&3) of rows
    // [0,64) and [64,128) for both A and B tiles.
    const int srow = tid >> 2;
    const int sq   = tid & 3;
    const short8* gA0 = reinterpret_cast<const short8*>(A  + (size_t)(i0base + srow)      * 256 + sq * 8);
    const short8* gA1 = reinterpret_cast<const short8*>(A  + (size_t)(i0base + srow + 64) * 256 + sq * 8);
    const short8* gB0 = reinterpret_cast<const short8*>(Bm + (size_t)(j0base + srow)      * 256 + sq * 8);
    const short8* gB1 = reinterpret_cast<const short8*>(Bm + (size_t)(j0base + srow + 64) * 256 + sq * 8);
    const int lO0 = srow * LDA + sq * 8;
    const int lO1 = (srow + 64) * LDA + sq * 8;

    // Preload chunk 0 -> buf 0.
    {
        short8 ra0 = gA0[0], ra1 = gA1[0], rb0 = gB0[0], rb1 = gB1[0];
        *reinterpret_cast<short8*>(&Ab[0][lO0]) = ra0;
        *reinterpret_cast<short8*>(&Ab[0][lO1]) = ra1;
        *reinterpret_cast<short8*>(&Bb[0][lO0]) = rb0;
        *reinterpret_cast<short8*>(&Bb[0][lO1]) = rb1;
    }
    __syncthreads();

    floatx4 acc[4][4];
    #pragma unroll
    for (int mt = 0; mt < 4; ++mt)
        #pragma unroll
        for (int nt = 0; nt < 4; ++nt) acc[mt][nt] = (floatx4){0.f, 0.f, 0.f, 0.f};

    #pragma unroll
    for (int c = 0; c < 8; ++c) {
        const int cb = c & 1;
        short8 na0, na1, nb0, nb1;
        if (c < 7) {                      // issue next chunk's global loads
            na0 = gA0[(c + 1) * 4]; na1 = gA1[(c + 1) * 4];
            nb0 = gB0[(c + 1) * 4]; nb1 = gB1[(c + 1) * 4];
        }
        short8 af[4], bfr[4];
        #pragma unroll
        for (int mt = 0; mt < 4; ++mt)
            af[mt] = *reinterpret_cast<const short8*>(&Ab[cb][(wr * 64 + mt * 16 + l16) * LDA + quad * 8]);
        #pragma unroll
        for (int nt = 0; nt < 4; ++nt)
            bfr[nt] = *reinterpret_cast<const short8*>(&Bb[cb][(wc * 64 + nt * 16 + l16) * LDA + quad * 8]);
        #pragma unroll
        for (int mt = 0; mt < 4; ++mt)
            #pragma unroll
            for (int nt = 0; nt < 4; ++nt)
                acc[mt][nt] = __builtin_amdgcn_mfma_f32_16x16x32_bf16(af[mt], bfr[nt], acc[mt][nt], 0, 0, 0);
        if (c < 7) {                      // stage next chunk after MFMA burst
            *reinterpret_cast<short8*>(&Ab[1 - cb][lO0]) = na0;
            *reinterpret_cast<short8*>(&Ab[1 - cb][lO1]) = na1;
            *reinterpret_cast<short8*>(&Bb[1 - cb][lO0]) = nb0;
            *reinterpret_cast<short8*>(&Bb[1 - cb][lO1]) = nb1;
            __syncthreads();
        }
    }

    // ---- Epilogue: LDS transpose -> skew-2 staircase full-line stores -----
    // C/D layout col=lane&15, row=quad*4+reg (m89-verified). Each wave owns a
    // private 8KB region (64 cols x 64 rows bf16, col-major, 16B units
    // XOR-swizzled by (col&7)). Wave-local RAW -> no barrier between write
    // and read. One __syncthreads first: regions alias Ab[1]/Bb[*], which
    // other waves still read in chunk 7.
    __syncthreads();
    short* ep = &Sb[0][0] + wave * 4096;
    #pragma unroll
    for (int mt = 0; mt < 4; ++mt) {
        const int ibase = i0base + wr * 64 + mt * 16 + quad * 4;
        const float4 nv = *reinterpret_cast<const float4*>(nA + ibase);
        const int u   = 2 * mt + (quad >> 1);   // logical 16B-unit (0..7)
        const int sub = (quad & 1) * 4;         // short offset within unit
        #pragma unroll
        for (int nt = 0; nt < 4; ++nt) {
            const int cl = nt * 16 + l16;       // local col 0..63
            const float y2 = nB[j0base + wc * 64 + cl];
            ushort4 pk;
            pk.x = f2bf(nv.x + y2 - 2.0f * acc[mt][nt][0]);
            pk.y = f2bf(nv.y + y2 - 2.0f * acc[mt][nt][1]);
            pk.z = f2bf(nv.z + y2 - 2.0f * acc[mt][nt][2]);
            pk.w = f2bf(nv.w + y2 - 2.0f * acc[mt][nt][3]);
            const int pu = u ^ (cl & 7);
            *reinterpret_cast<ushort4*>(ep + cl * 64 + pu * 8 + sub) = pk;
        }
    }
    // Anti-diagonal readout (skew-2): lane (a=l>>3, r=l&7) supplies unit r of
    // local col cl = s_off - 2r (s_off = a0*8 + a) -> global chunk q = R0+r,
    // col j = J0+cl, row s2 = j + 2q = S2base + s_off, S2base = J0 + 2*R0.
    // For each s2-row the 8 r-lanes write (R0+r)*16B consecutive = one FULL
    // aligned 128B line (R0 mult of 8). s_off range 0..77 -> a0 0..9.
    {
        const int R0     = (i0base + wr * 64) >> 3;     // global 8-row index
        const int S2base = j0base + wc * 64 + 2 * R0;
        const int a = lane >> 3, r = lane & 7;
        #pragma unroll
        for (int a0 = 0; a0 < 10; ++a0) {
            const int s_off = a0 * 8 + a;
            const int cl = s_off - 2 * r;               // local col
            if (cl >= 0 && cl < 64) {
                const int pu = r ^ (cl & 7);
                const short8 v = *reinterpret_cast<const short8*>(ep + cl * 64 + pu * 8);
                *reinterpret_cast<short8*>(
                    Dmat + (size_t)(S2base + s_off) * 512 + (R0 + r) * 8) = v;
            }
        }
    }
}

// ---- Phase 3: one-wave hardmin DTW, plain-load reg pipeline, 2-col steps --
// grid 192 x 64 threads (one wave). Lane t owns rows [8t, 8t+8).
// Super-step S: lane t computes cols jA=2(S-t), jB=jA+1 (valid iff
// 0<=jA<=510). 80 groups x 4 super-steps; group g = s2-rows 8g..8g+7;
// lane t's 16B for row s2 at byte (s2*1024 + t*16) -> 8 coalesced
// global_load_dwordx4 per group (plain C loads: compiler tracks vmcnt and
// inserts minimal counted waits before first use). Depth-2 pipeline B0/B1
// (64 VGPR): group g's loads issue at end of PROC(g-2), ~800cy before use.
// sched_barrier(0) fences pin the load clusters (no sinking, rule-#18-safe
// since waits are compiler-owned).
// Cross-lane state: pA=R[8t-1,jA], pB=R[8t-1,jB], pL=R[8t-1,jA-1];
// pL'=pB, pA'=dpp(botA), pB'=dpp(botB) (lane0 -> BIG).
// Init pL = (t==0 ? 0 : BIG) handles the DP origin (jA==0 at S=t).

#define DTW_LOADG(B, gidx)                                                    \
    {                                                                         \
        int s8_ = (gidx) * 8;                                                 \
        if (s8_ > 632) s8_ = 632;   /* keep rows in [0,640) (pad rows) */     \
        const uint4* p_ = Dcol + (size_t)s8_ * 64;                            \
        B[0] = p_[0];   B[1] = p_[64];  B[2] = p_[128]; B[3] = p_[192];       \
        B[4] = p_[256]; B[5] = p_[320]; B[6] = p_[384]; B[7] = p_[448];       \
    }

#define DTW_UNPACK1(buf, d)                                                   \
    d[0] = bf2f_lo(buf.x); d[1] = bf2f_hi(buf.x);                             \
    d[2] = bf2f_lo(buf.y); d[3] = bf2f_hi(buf.y);                             \
    d[4] = bf2f_lo(buf.z); d[5] = bf2f_hi(buf.z);                             \
    d[6] = bf2f_lo(buf.w); d[7] = bf2f_hi(buf.w);

// Core 2-col cell block (no guards). Col A: diag/top from (pL,pA), left from
// prev[]. Col B: diag/top from (pA,pB)/chain, left from col A. min3-fused.
#define DTW_CELLS2(ca, cb)                                                    \
    {                                                                         \
        float dA[8], dB[8];                                                   \
        DTW_UNPACK1(ca, dA)                                                   \
        DTW_UNPACK1(cb, dB)                                                   \
        float cA[8], cB[8];                                                   \
        cA[0] = dA[0] + fminf(fminf(pL, pA), prev[0]);                        \
        _Pragma("unroll")                                                     \
        for (int r = 1; r < 8; ++r)                                           \
            cA[r] = dA[r] + fminf(fminf(prev[r - 1], prev[r]), cA[r - 1]);    \
        cB[0] = dB[0] + fminf(fminf(pA, pB), cA[0]);                          \
        _Pragma("unroll")                                                     \
        for (int r = 1; r < 8; ++r)                                           \
            cB[r] = dB[r] + fminf(fminf(cA[r - 1], cB[r - 1]), cA[r]);        \
        _Pragma("unroll")                                                     \
        for (int r = 0; r < 8; ++r) prev[r] = cB[r];                          \
        botA = cA[7]; botB = cB[7];                                           \
    }

// Cross-lane handoff (all lanes, every super-step).
#define DTW_HANDOFF                                                           \
    {                                                                         \
        const float rA_ = dpp_shr1(botA);                                     \
        const float rB_ = dpp_shr1(botB);                                     \
        pL = pB;                                                              \
        pA = (t == 0) ? SDTW_BIG : rA_;                                       \
        pB = (t == 0) ? SDTW_BIG : rB_;                                       \
    }

// Fast super-step (all lanes valid).
#define DTW_SSF(ca, cb, Sv)                                                   \
    {                                                                         \
        DTW_CELLS2(ca, cb)                                                    \
        DTW_HANDOFF                                                           \
    }

// Guarded super-step (ramps): compute only if 0 <= jA <= 510.
#define DTW_SSG(ca, cb, Sv)                                                   \
    {                                                                         \
        const int jA_ = 2 * ((Sv) - t);                                       \
        if (jA_ >= 0 && jA_ <= 510) {                                         \
            DTW_CELLS2(ca, cb)                                                \
        }                                                                     \
        DTW_HANDOFF                                                           \
    }

// One group: [fence] compute 4 super-steps from B (compiler inserts the
// counted vmcnt wait before B's first use) [fence] reissue B with group g+2.
#define DTW_PROC(B, g, SS)                                                    \
    {                                                                         \
        __builtin_amdgcn_sched_barrier(0);                                    \
        SS(B[0], B[1], 4 * (g) + 0)                                           \
        SS(B[2], B[3], 4 * (g) + 1)                                           \
        SS(B[4], B[5], 4 * (g) + 2)                                           \
        SS(B[6], B[7], 4 * (g) + 3)                                           \
        __builtin_amdgcn_sched_barrier(0);                                    \
        DTW_LOADG(B, (g) + 2)                                                 \
    }

__global__ __launch_bounds__(64) void dtw_wave_kernel(
    const unsigned short* __restrict__ Dws, float* __restrict__ out) {
    const int z = blockIdx.x;            // p*64 + b
    const int p = z >> 6;
    const int b = z & 63;
    const unsigned short* Dmat = Dws + (size_t)z * DMAT_ELEMS;
    const int t = threadIdx.x;           // lane 0..63
    const uint4* Dcol = reinterpret_cast<const uint4*>(Dmat) + t;  // +s2*64

    float prev[8];                        // R[8t+r, jB] of last super-step
    #pragma unroll
    for (int r = 0; r < 8; ++r) prev[r] = SDTW_BIG;
    float botA = SDTW_BIG, botB = SDTW_BIG;
    float pA = SDTW_BIG, pB = SDTW_BIG;
    float pL = (t == 0) ? 0.0f : SDTW_BIG;   // DP origin: R[-1,-1]=0 for lane0

    uint4 B0[8], B1[8];

    // Prologue: fill the depth-2 pipeline (groups 0,1 -> 16 loads in flight).
    DTW_LOADG(B0, 0)
    DTW_LOADG(B1, 1)

    // Guarded ramp-up: groups 0..15 (S 0..63; lanes activate at S=t,
    // jA==0 cases handled by pL init + guard).
    #pragma clang loop unroll(disable)
    for (int blk = 0; blk < 8; ++blk) {
        const int g = blk * 2;
        DTW_PROC(B0, g + 0, DTW_SSG)
        DTW_PROC(B1, g + 1, DTW_SSG)
    }
    // Fast: groups 16..63 (S 64..255: all lanes valid, jA!=0).
    #pragma clang loop unroll(disable)
    for (int blk = 8; blk < 32; ++blk) {
        const int g = blk * 2;
        DTW_PROC(B0, g + 0, DTW_SSF)
        DTW_PROC(B1, g + 1, DTW_SSF)
    }
    // Guarded ramp-down: groups 64..79 (S 256..319; lanes retire as jA>510;
    // load side clamps to row 632, dead prefetches never consumed).
    #pragma clang loop unroll(disable)
    for (int blk = 32; blk < 40; ++blk) {
        const int g = blk * 2;
        DTW_PROC(B0, g + 0, DTW_SSG)
        DTW_PROC(B1, g + 1, DTW_SSG)
    }

    if (t == 63) {                // botB == R[511,511] (S=318: jB=511)
        const float coef = (p == 0) ? 1.0f : -0.5f;
        atomicAdd(&out[b], coef * botB);
    }
}

extern "C" void kernel_launch(void* const* d_in, const int* in_sizes, int n_in,
                              void* d_out, int out_size, void* d_ws, size_t ws_size,
                              hipStream_t stream) {
    const float* x = (const float*)d_in[0];
    const float* y = (const float*)d_in[1];
    float* out = (float*)d_out;
    char* ws = (char*)d_ws;

    // ws layout (bytes):
    //   [0, 125829120)              D bf16 skew-2 staircase, 192 x 327680
    //   [125829120, 142606336)      xb bf16
    //   [142606336, 159383552)      yb bf16
    //   [159383552, 159514624)      nx fp32
    //   [159514624, 159645696)      ny fp32
    unsigned short* Dws = (unsigned short*)ws;
    unsigned short* xb  = (unsigned short*)(ws + 125829120);
    unsigned short* yb  = (unsigned short*)(ws + 142606336);
    float* nx = (float*)(ws + 159383552);
    float* ny = (float*)(ws + 159514624);

    hipMemsetAsync(d_out, 0, 64 * sizeof(float), stream);
    convert_norm_kernel<<<dim3(8192, 2), 256, 0, stream>>>(x, y, xb, yb, nx, ny);
    gemm_lds_kernel<<<3072, 256, 0, stream>>>(xb, yb, nx, ny, Dws);
    dtw_wave_kernel<<<192, 64, 0, stream>>>(Dws, out);
}